// Round 7
// baseline (350.208 us; speedup 1.0000x reference)
//
#include <hip/hip_runtime.h>

typedef __bf16 bf16x8 __attribute__((ext_vector_type(8)));
typedef float f32x4 __attribute__((ext_vector_type(4)));

__device__ inline unsigned short f2bf(float f) {
    unsigned x = __builtin_bit_cast(unsigned, f);
    x += 0x7fffu + ((x >> 16) & 1u);   // RNE
    return (unsigned short)(x >> 16);
}
__device__ inline unsigned pack2bf(float lo, float hi) {
    return (unsigned)f2bf(lo) | ((unsigned)f2bf(hi) << 16);
}
__device__ inline void cvt8(uint4 u, float* o) {
    o[0] = __builtin_bit_cast(float, u.x << 16);
    o[1] = __builtin_bit_cast(float, u.x & 0xffff0000u);
    o[2] = __builtin_bit_cast(float, u.y << 16);
    o[3] = __builtin_bit_cast(float, u.y & 0xffff0000u);
    o[4] = __builtin_bit_cast(float, u.z << 16);
    o[5] = __builtin_bit_cast(float, u.z & 0xffff0000u);
    o[6] = __builtin_bit_cast(float, u.w << 16);
    o[7] = __builtin_bit_cast(float, u.w & 0xffff0000u);
}
// exact-erf GELU via Abramowitz-Stegun 7.1.26 (|err| <= 1.5e-7)
__device__ inline float gelu_f(float v) {
    float x = fabsf(v) * 0.70710678118654752f;
    float td = __builtin_amdgcn_rcpf(1.0f + 0.3275911f * x);
    float p = ((((1.061405429f * td - 1.453152027f) * td + 1.421413741f) * td
                - 0.284496736f) * td + 0.254829592f) * td;
    float e = __expf(-x * x);
    float er = 1.0f - p * e;
    float s = v < 0.0f ? -er : er;
    return 0.5f * v * (1.0f + s);
}

// async global->LDS, 16B per lane (emits global_load_lds_dwordx4)
__device__ inline void gload_lds16(const void* g, void* l) {
    typedef __attribute__((address_space(1))) const unsigned int gq;
    typedef __attribute__((address_space(3))) unsigned int sq;
    __builtin_amdgcn_global_load_lds((gq*)g, (sq*)l, 16, 0, 0);
}

// W pad: 164 shorts/row -> LDS tile 160*164*2 = 52480 B <= 53333 B
// -> 3 blocks/CU resident (was 168 -> 53760 B -> only 2 blocks/CU).
#define WPAD 164
#define WELEMS (160 * WPAD)          // 26240 shorts per matrix
#define WCHUNKS (WELEMS * 2 / 16)    // 3280 16B chunks

// ---------------------------------------------------------------------------
// prep_w3: all three W (fp32 160x160) -> bf16 W^T, PADDED [co][WPAD], in d_ws.
// ---------------------------------------------------------------------------
__global__ __launch_bounds__(256) void prep_w3(const float* __restrict__ W1,
                                               const float* __restrict__ W2,
                                               const float* __restrict__ W3,
                                               unsigned short* __restrict__ dst) {
    int e = blockIdx.x * 256 + threadIdx.x;  // 3*WELEMS total
    if (e >= 3 * WELEMS) return;
    int m = e / WELEMS;
    int r = e - m * WELEMS;
    int co = r / WPAD, ci = r - co * WPAD;
    const float* W = (m == 0) ? W1 : (m == 1) ? W2 : W3;
    dst[e] = (ci < 160) ? f2bf(W[ci * 160 + co]) : (unsigned short)0;
}

template <int AXIS, bool FP32IN>
__device__ inline void load_a_raw(const void* __restrict__ Xv, int row, uint4* u,
                                  float4* f, int kq) {
    const int n = row & 32767;
    const int coord = (AXIS == 0) ? (n >> 10) : (AXIS == 1) ? ((n >> 5) & 31) : (n & 31);
    const int stride = (AXIS == 0) ? 1024 : (AXIS == 1) ? 32 : 1;
#pragma unroll
    for (int g = 0; g < 5; g++) {
        int s = 2 - g;
        bool ok = (unsigned)(coord + s) < 32u;
        int srow = ok ? row + s * stride : row;
        size_t off = (size_t)srow * 160 + g * 32 + kq * 8;
        if (FP32IN) {
            const float* p = (const float*)Xv + off;
            float4 r0 = ((const float4*)p)[0];
            float4 r1 = ((const float4*)p)[1];
            if (!ok) { r0 = make_float4(0, 0, 0, 0); r1 = make_float4(0, 0, 0, 0); }
            f[g * 2] = r0; f[g * 2 + 1] = r1;
        } else {
            uint4 v = *(const uint4*)((const unsigned short*)Xv + off);
            if (!ok) v = make_uint4(0, 0, 0, 0);
            u[g] = v;
        }
    }
}

template <bool FP32IN>
__device__ inline void pack_a(const uint4* u, const float4* f, uint4* a) {
#pragma unroll
    for (int g = 0; g < 5; g++) {
        if (FP32IN) {
            float4 r0 = f[g * 2], r1 = f[g * 2 + 1];
            a[g] = make_uint4(pack2bf(r0.x, r0.y), pack2bf(r0.z, r0.w),
                              pack2bf(r1.x, r1.y), pack2bf(r1.z, r1.w));
        } else {
            a[g] = u[g];
        }
    }
}

// Both tiles share each wf read. acc[nt][r] = Y[xrow][co = nt*16 + kq*4 + r].
__device__ inline void tile_compute_both(const unsigned short* __restrict__ lw,
                                         const uint4* a0, const uint4* a1,
                                         f32x4* acc0, f32x4* acc1, int mr, int kq) {
#pragma unroll
    for (int g = 0; g < 5; g++) {
        bf16x8 x0 = __builtin_bit_cast(bf16x8, a0[g]);
        bf16x8 x1 = __builtin_bit_cast(bf16x8, a1[g]);
        const unsigned short* bp = lw + mr * WPAD + g * 32 + kq * 8;
#pragma unroll
        for (int nt = 0; nt < 10; nt++) {
            bf16x8 wf = __builtin_bit_cast(bf16x8, *(const uint4*)(bp + nt * 16 * WPAD));
            acc0[nt] = __builtin_amdgcn_mfma_f32_16x16x32_bf16(wf, x0, acc0[nt], 0, 0, 0);
            acc1[nt] = __builtin_amdgcn_mfma_f32_16x16x32_bf16(wf, x1, acc1[nt], 0, 0, 0);
        }
    }
}

// Bias(+GELU) -> stage wave's 16x160 tile in LDS slot -> coalesced stores.
// Slot strides independent of WPAD; fit inside 52480 B:
//   bf16: 8 slots x 16x168 shorts = 43008 B.  fp32: 4 slots x 16x164 f = 41984 B.
template <bool GELU, bool F32OUT>
__device__ inline void stage_store(unsigned short* __restrict__ lbase,
                                   const f32x4* acc, const float* __restrict__ Bs,
                                   void* __restrict__ Yv, int rowbase,
                                   int lane, int slot, int mr, int kq) {
    if (F32OUT) {
        float* sw = (float*)lbase + slot * (16 * 164);
#pragma unroll
        for (int nt = 0; nt < 10; nt++) {
            float4 bb = *(const float4*)(Bs + nt * 16 + kq * 4);
            float v0 = acc[nt][0] + bb.x, v1 = acc[nt][1] + bb.y,
                  v2 = acc[nt][2] + bb.z, v3 = acc[nt][3] + bb.w;
            if (GELU) { v0 = gelu_f(v0); v1 = gelu_f(v1); v2 = gelu_f(v2); v3 = gelu_f(v3); }
            *(float4*)(sw + mr * 164 + nt * 16 + kq * 4) = make_float4(v0, v1, v2, v3);
        }
#pragma unroll
        for (int p = 0; p < 10; p++) {
            int idx = p * 256 + lane * 4;
            int row = idx / 160;
            int col = idx - row * 160;
            float4 v = *(const float4*)(sw + row * 164 + col);
            *(float4*)((float*)Yv + (size_t)rowbase * 160 + idx) = v;
        }
    } else {
        unsigned short* sw = lbase + slot * (16 * 168);
#pragma unroll
        for (int nt = 0; nt < 10; nt++) {
            float4 bb = *(const float4*)(Bs + nt * 16 + kq * 4);
            float v0 = acc[nt][0] + bb.x, v1 = acc[nt][1] + bb.y,
                  v2 = acc[nt][2] + bb.z, v3 = acc[nt][3] + bb.w;
            if (GELU) { v0 = gelu_f(v0); v1 = gelu_f(v1); v2 = gelu_f(v2); v3 = gelu_f(v3); }
            uint2 pk;
            pk.x = pack2bf(v0, v1);
            pk.y = pack2bf(v2, v3);
            *(uint2*)(sw + mr * 168 + nt * 16 + kq * 4) = pk;
        }
#pragma unroll
        for (int p = 0; p < 5; p++) {
            int idx = p * 512 + lane * 8;
            int row = idx / 160;
            int col = idx - row * 160;
            uint4 v = *(const uint4*)(sw + row * 168 + col);
            *(uint4*)((unsigned short*)Yv + (size_t)rowbase * 160 + idx) = v;
        }
    }
}

// ---------------------------------------------------------------------------
// R11: T=2 (revert of the T=4 spill regression: VGPR 128 + scratch) with
// WPAD=164 -> 52480 B LDS -> 3 blocks/CU (was 2). Latency-bound kernel:
// +50% resident waves is the lever.
// ---------------------------------------------------------------------------
template <int AXIS, bool GELU, bool FP32IN, bool F32OUT>
__global__ __launch_bounds__(256, 3) void gemm_shift(
    const void* __restrict__ Xv, const unsigned short* __restrict__ Wt,
    const float* __restrict__ Bs, void* __restrict__ Yv) {
    __shared__ unsigned short lw[WELEMS];  // W^T bf16: [co][ci], 52480 B
    const int t = threadIdx.x;
    const int lane = t & 63, wv = t >> 6, mr = lane & 15, kq = lane >> 4;
    const int rbase = blockIdx.x * 128;

    // async W DMA first (starts earliest, no VGPR use): 3280 16B chunks
    for (int i = t; i < WCHUNKS; i += 256)
        gload_lds16((const char*)Wt + i * 16, (char*)lw + i * 16);

    // prefetch BOTH A tiles while the DMA flows
    uint4 u0[5], u1[5];
    float4 f0[10], f1[10];
    load_a_raw<AXIS, FP32IN>(Xv, rbase + wv * 16 + mr, u0, f0, kq);
    load_a_raw<AXIS, FP32IN>(Xv, rbase + 64 + wv * 16 + mr, u1, f1, kq);

    __syncthreads();  // drains vmcnt (W DMA) + our A loads

    uint4 a0[5], a1[5];
    pack_a<FP32IN>(u0, f0, a0);
    pack_a<FP32IN>(u1, f1, a1);
    f32x4 acc0[10] = {};
    f32x4 acc1[10] = {};
    tile_compute_both(lw, a0, a1, acc0, acc1, mr, kq);

    __syncthreads();  // all waves done reading W -> lw reusable as staging
    const int slot0 = wv;
    const int slot1 = F32OUT ? wv : wv + 4;  // bf16 fits 8 slots: no serialization
    stage_store<GELU, F32OUT>(lw, acc0, Bs, Yv, rbase + wv * 16, lane, slot0, mr, kq);
    stage_store<GELU, F32OUT>(lw, acc1, Bs, Yv, rbase + 64 + wv * 16, lane, slot1, mr, kq);
}

// ---------------------------------------------------------------------------
// Depthwise 3x3x3 SAME conv + bias. (R8 XCD chunk swizzle kept; UNCHANGED.)
// ---------------------------------------------------------------------------
__global__ __launch_bounds__(256) void dwconv3(
    const unsigned short* __restrict__ X, const float* __restrict__ Kw,
    const float* __restrict__ Bs, unsigned short* __restrict__ Y) {
    __shared__ float wl[20 * 220];
    const int t = threadIdx.x;
    for (int e = t; e < 160 * 27; e += 256) {
        int c = e / 27, tap = e % 27;
        wl[(c >> 3) * 220 + tap * 8 + (c & 7)] = Kw[e];
    }
    __syncthreads();

    // bijective XCD swizzle: 2560 blocks = 8 XCDs x 320-block contiguous chunks
    int bid = blockIdx.x;
    int swz = (bid & 7) * 320 + (bid >> 3);
    int idx = swz * 256 + t;

    int cc = idx % 20;
    int r = idx / 20;
    int dq = r & 7;  r >>= 3;
    int w = r & 31;  r >>= 5;
    int h = r & 31;
    int b = r >> 5;
    int d0 = dq << 2;

    float acc[4][8];
    {
        float bv[8];
        *(float4*)&bv[0] = ((const float4*)(Bs + cc * 8))[0];
        *(float4*)&bv[4] = ((const float4*)(Bs + cc * 8))[1];
#pragma unroll
        for (int od = 0; od < 4; od++)
#pragma unroll
            for (int j = 0; j < 8; j++) acc[od][j] = bv[j];
    }
    const float* wbase = &wl[cc * 220];
#pragma unroll
    for (int dh = -1; dh <= 1; dh++) {
        int hh = h + dh;
        if ((unsigned)hh >= 32u) continue;
#pragma unroll
        for (int dwi = -1; dwi <= 1; dwi++) {
            int ww = w + dwi;
            if ((unsigned)ww >= 32u) continue;
            const unsigned short* base =
                X + (size_t)(b * 32768 + hh * 1024 + ww * 32) * 160 + cc * 8;
            int tap0 = (dh + 1) * 9 + (dwi + 1) * 3;
            float wv_[24];
#pragma unroll
            for (int q2 = 0; q2 < 6; q2++)
                ((float4*)wv_)[q2] = *(const float4*)(wbase + tap0 * 8 + q2 * 4);
            // hoist the 6 raw loads, then convert (independent issue)
            uint4 ub[6];
#pragma unroll
            for (int dd = 0; dd < 6; dd++) {
                int d = d0 - 1 + dd;
                ub[dd] = ((unsigned)d < 32u) ? *(const uint4*)(base + d * 160)
                                             : make_uint4(0, 0, 0, 0);
            }
            float vb[6][8];
#pragma unroll
            for (int dd = 0; dd < 6; dd++) cvt8(ub[dd], vb[dd]);
#pragma unroll
            for (int od = 0; od < 4; od++)
#pragma unroll
                for (int dd = 0; dd < 3; dd++)
#pragma unroll
                    for (int j = 0; j < 8; j++)
                        acc[od][j] += vb[od + dd][j] * wv_[dd * 8 + j];
        }
    }
#pragma unroll
    for (int od = 0; od < 4; od++) {
        unsigned short tmp[8];
#pragma unroll
        for (int j = 0; j < 8; j++) tmp[j] = f2bf(acc[od][j]);
        *(uint4*)(Y + (size_t)(b * 32768 + h * 1024 + w * 32 + d0 + od) * 160 + cc * 8) =
            *(uint4*)tmp;
    }
}

// ---------------------------------------------------------------------------
// Pipeline: prep_w3 -> shiftH+GEMM1 -> dw1 -> shiftW+GEMM2 -> dw2 ->
//           shiftD+GEMM3+GELU.  Intermediates in d_ws (R9 layout kept).
// ---------------------------------------------------------------------------
extern "C" void kernel_launch(void* const* d_in, const int* in_sizes, int n_in,
                              void* d_out, int out_size, void* d_ws, size_t ws_size,
                              hipStream_t stream) {
    const void*  x    = d_in[0];                    // fp32 (B,N,C)
    const float* w1   = (const float*)d_in[4];
    const float* b1   = (const float*)d_in[5];
    const float* dw1  = (const float*)d_in[6];
    const float* bdw1 = (const float*)d_in[7];
    const float* w2   = (const float*)d_in[8];
    const float* b2   = (const float*)d_in[9];
    const float* dw2  = (const float*)d_in[10];
    const float* bdw2 = (const float*)d_in[11];
    const float* w3   = (const float*)d_in[12];
    const float* b3   = (const float*)d_in[13];

    unsigned short* wbf = (unsigned short*)d_ws;   // 3 x WELEMS bf16 W^T padded

    const size_t BUF_BYTES = (size_t)4 * 32768 * 160 * 2;  // 41,943,040 B
    const size_t OFF_A = 2u << 20;                          // 2 MiB
    const size_t OFF_B = OFF_A + BUF_BYTES;
    unsigned short* bufA;
    unsigned short* bufB;
    if (ws_size >= OFF_B + BUF_BYTES) {
        bufA = (unsigned short*)((char*)d_ws + OFF_A);      // clean: ws only
        bufB = (unsigned short*)((char*)d_ws + OFF_B);
    } else {
        bufA = (unsigned short*)d_out;                      // fallback
        bufB = (unsigned short*)d_in[0];
    }

    prep_w3<<<(3 * WELEMS + 255) / 256, 256, 0, stream>>>(w1, w2, w3, wbf);
    gemm_shift<0, false, true,  false><<<1024, 256, 0, stream>>>(x,    wbf,              b1, bufA);
    dwconv3<<<2560, 256, 0, stream>>>(bufA, dw1, bdw1, bufB);
    gemm_shift<1, false, false, false><<<1024, 256, 0, stream>>>(bufB, wbf + WELEMS,     b2, bufA);
    dwconv3<<<2560, 256, 0, stream>>>(bufA, dw2, bdw2, bufB);
    gemm_shift<2, true,  false, true ><<<1024, 256, 0, stream>>>(bufB, wbf + 2 * WELEMS, b3, d_out);
}

// Round 8
// 303.528 us; speedup vs baseline: 1.1538x; 1.1538x over previous
//
#include <hip/hip_runtime.h>

typedef __bf16 bf16x8 __attribute__((ext_vector_type(8)));
typedef float f32x4 __attribute__((ext_vector_type(4)));

__device__ inline unsigned short f2bf(float f) {
    unsigned x = __builtin_bit_cast(unsigned, f);
    x += 0x7fffu + ((x >> 16) & 1u);   // RNE
    return (unsigned short)(x >> 16);
}
__device__ inline unsigned pack2bf(float lo, float hi) {
    return (unsigned)f2bf(lo) | ((unsigned)f2bf(hi) << 16);
}
__device__ inline void cvt8(uint4 u, float* o) {
    o[0] = __builtin_bit_cast(float, u.x << 16);
    o[1] = __builtin_bit_cast(float, u.x & 0xffff0000u);
    o[2] = __builtin_bit_cast(float, u.y << 16);
    o[3] = __builtin_bit_cast(float, u.y & 0xffff0000u);
    o[4] = __builtin_bit_cast(float, u.z << 16);
    o[5] = __builtin_bit_cast(float, u.z & 0xffff0000u);
    o[6] = __builtin_bit_cast(float, u.w << 16);
    o[7] = __builtin_bit_cast(float, u.w & 0xffff0000u);
}
// exact-erf GELU via Abramowitz-Stegun 7.1.26 (|err| <= 1.5e-7)
__device__ inline float gelu_f(float v) {
    float x = fabsf(v) * 0.70710678118654752f;
    float td = __builtin_amdgcn_rcpf(1.0f + 0.3275911f * x);
    float p = ((((1.061405429f * td - 1.453152027f) * td + 1.421413741f) * td
                - 0.284496736f) * td + 0.254829592f) * td;
    float e = __expf(-x * x);
    float er = 1.0f - p * e;
    float s = v < 0.0f ? -er : er;
    return 0.5f * v * (1.0f + s);
}

// async global->LDS, 16B per lane (emits global_load_lds_dwordx4)
__device__ inline void gload_lds16(const void* g, void* l) {
    typedef __attribute__((address_space(1))) const unsigned int gq;
    typedef __attribute__((address_space(3))) unsigned int sq;
    __builtin_amdgcn_global_load_lds((gq*)g, (sq*)l, 16, 0, 0);
}

// W pad back to the proven-good 168 (R11's 164 regressed: no 3rd block
// materialized, occupancy stayed ~24%, gemm 75us).
#define WPAD 168
#define WELEMS (160 * WPAD)          // 26880 shorts per matrix
#define WCHUNKS (WELEMS * 2 / 16)    // 3360 16B chunks

// ---------------------------------------------------------------------------
// prep_w3: all three W (fp32 160x160) -> bf16 W^T, PADDED [co][WPAD], in d_ws.
// ---------------------------------------------------------------------------
__global__ __launch_bounds__(256) void prep_w3(const float* __restrict__ W1,
                                               const float* __restrict__ W2,
                                               const float* __restrict__ W3,
                                               unsigned short* __restrict__ dst) {
    int e = blockIdx.x * 256 + threadIdx.x;  // 3*WELEMS = 80640 total
    if (e >= 3 * WELEMS) return;
    int m = e / WELEMS;
    int r = e - m * WELEMS;
    int co = r / WPAD, ci = r - co * WPAD;
    const float* W = (m == 0) ? W1 : (m == 1) ? W2 : W3;
    dst[e] = (ci < 160) ? f2bf(W[ci * 160 + co]) : (unsigned short)0;
}

template <int AXIS, bool FP32IN>
__device__ inline void load_a_raw(const void* __restrict__ Xv, int row, uint4* u,
                                  float4* f, int kq) {
    const int n = row & 32767;
    const int coord = (AXIS == 0) ? (n >> 10) : (AXIS == 1) ? ((n >> 5) & 31) : (n & 31);
    const int stride = (AXIS == 0) ? 1024 : (AXIS == 1) ? 32 : 1;
#pragma unroll
    for (int g = 0; g < 5; g++) {
        int s = 2 - g;
        bool ok = (unsigned)(coord + s) < 32u;
        int srow = ok ? row + s * stride : row;
        size_t off = (size_t)srow * 160 + g * 32 + kq * 8;
        if (FP32IN) {
            const float* p = (const float*)Xv + off;
            float4 r0 = ((const float4*)p)[0];
            float4 r1 = ((const float4*)p)[1];
            if (!ok) { r0 = make_float4(0, 0, 0, 0); r1 = make_float4(0, 0, 0, 0); }
            f[g * 2] = r0; f[g * 2 + 1] = r1;
        } else {
            uint4 v = *(const uint4*)((const unsigned short*)Xv + off);
            if (!ok) v = make_uint4(0, 0, 0, 0);
            u[g] = v;
        }
    }
}

template <bool FP32IN>
__device__ inline void pack_a(const uint4* u, const float4* f, uint4* a) {
#pragma unroll
    for (int g = 0; g < 5; g++) {
        if (FP32IN) {
            float4 r0 = f[g * 2], r1 = f[g * 2 + 1];
            a[g] = make_uint4(pack2bf(r0.x, r0.y), pack2bf(r0.z, r0.w),
                              pack2bf(r1.x, r1.y), pack2bf(r1.z, r1.w));
        } else {
            a[g] = u[g];
        }
    }
}

// Both tiles share each wf read. acc[nt][r] = Y[xrow][co = nt*16 + kq*4 + r].
__device__ inline void tile_compute_both(const unsigned short* __restrict__ lw,
                                         const uint4* a0, const uint4* a1,
                                         f32x4* acc0, f32x4* acc1, int mr, int kq) {
#pragma unroll
    for (int g = 0; g < 5; g++) {
        bf16x8 x0 = __builtin_bit_cast(bf16x8, a0[g]);
        bf16x8 x1 = __builtin_bit_cast(bf16x8, a1[g]);
        const unsigned short* bp = lw + mr * WPAD + g * 32 + kq * 8;
#pragma unroll
        for (int nt = 0; nt < 10; nt++) {
            bf16x8 wf = __builtin_bit_cast(bf16x8, *(const uint4*)(bp + nt * 16 * WPAD));
            acc0[nt] = __builtin_amdgcn_mfma_f32_16x16x32_bf16(wf, x0, acc0[nt], 0, 0, 0);
            acc1[nt] = __builtin_amdgcn_mfma_f32_16x16x32_bf16(wf, x1, acc1[nt], 0, 0, 0);
        }
    }
}

// Epilogue A (bf16 out): bias -> pack -> stage in per-wave LDS slot (separate
// region, NOT lw) -> coalesced 1KB-line stores. Same-wave DS ordering makes
// sequential slot reuse safe without barriers.
__device__ inline void store_bf16_staged(unsigned short* __restrict__ stg,
                                         const f32x4* acc, const float* __restrict__ Bs,
                                         unsigned short* __restrict__ Yv, int rowbase,
                                         int lane, int wv, int mr, int kq) {
    unsigned short* sw = stg + wv * (16 * 168);
#pragma unroll
    for (int nt = 0; nt < 10; nt++) {
        float4 bb = *(const float4*)(Bs + nt * 16 + kq * 4);
        uint2 pk;
        pk.x = pack2bf(acc[nt][0] + bb.x, acc[nt][1] + bb.y);
        pk.y = pack2bf(acc[nt][2] + bb.z, acc[nt][3] + bb.w);
        *(uint2*)(sw + mr * 168 + nt * 16 + kq * 4) = pk;
    }
#pragma unroll
    for (int p = 0; p < 5; p++) {
        int idx = p * 512 + lane * 8;
        int row = idx / 160;
        int col = idx - row * 160;
        uint4 v = *(const uint4*)(sw + row * 168 + col);
        *(uint4*)(Yv + (size_t)rowbase * 160 + idx) = v;
    }
}

// Epilogue B (fp32 out, +GELU): DIRECT stores — swapped-MFMA layout gives
// 4 lanes x 16B contiguous per row at 64B-aligned offsets = full HBM
// sectors, no RMW. No staging, no barrier.
__device__ inline void store_f32_direct(const f32x4* acc, const float* __restrict__ Bs,
                                        float* __restrict__ Yv, int rowbase,
                                        int mr, int kq) {
    float* rp = Yv + (size_t)(rowbase + mr) * 160;
#pragma unroll
    for (int nt = 0; nt < 10; nt++) {
        float4 bb = *(const float4*)(Bs + nt * 16 + kq * 4);
        float4 v;
        v.x = gelu_f(acc[nt][0] + bb.x);
        v.y = gelu_f(acc[nt][1] + bb.y);
        v.z = gelu_f(acc[nt][2] + bb.z);
        v.w = gelu_f(acc[nt][3] + bb.w);
        *(float4*)(rp + nt * 16 + kq * 4) = v;
    }
}

// ---------------------------------------------------------------------------
// R12: persistent-W loop. Grid 512 (= exactly 2 resident/CU, one dispatch
// round); each block computes 256 rows as TWO sequential T=2 iterations
// reusing the W tile staged once (W-DMA traffic halved). Iteration-2 A-loads
// are issued into the SAME u/f arrays right after iteration-1's pack (arrays
// dead) -> overlap the whole iteration-1 compute with ZERO register growth
// (the R10 mistake was 4 live acc sets). One barrier total.
// ---------------------------------------------------------------------------
template <int AXIS, bool GELU, bool FP32IN, bool F32OUT>
__global__ __launch_bounds__(256, 2) void gemm_shift(
    const void* __restrict__ Xv, const unsigned short* __restrict__ Wt,
    const float* __restrict__ Bs, void* __restrict__ Yv) {
    __shared__ unsigned short lw[WELEMS];                       // 53760 B
    __shared__ unsigned short stg[F32OUT ? 1 : 4 * 16 * 168];   // 21504 B (bf16 only)
    const int t = threadIdx.x;
    const int lane = t & 63, wv = t >> 6, mr = lane & 15, kq = lane >> 4;
    const int rbase = blockIdx.x * 256;

    // async W DMA first (no VGPR use): 3360 16B chunks
    for (int i = t; i < WCHUNKS; i += 256)
        gload_lds16((const char*)Wt + i * 16, (char*)lw + i * 16);

    // prefetch iteration-1 A pair while the DMA flows
    uint4 u0[5], u1[5];
    float4 f0[10], f1[10];
    load_a_raw<AXIS, FP32IN>(Xv, rbase + wv * 16 + mr, u0, f0, kq);
    load_a_raw<AXIS, FP32IN>(Xv, rbase + 64 + wv * 16 + mr, u1, f1, kq);

    __syncthreads();  // drains vmcnt: W DMA + pair-1 loads. ONLY barrier.

    uint4 a0[5], a1[5];
    pack_a<FP32IN>(u0, f0, a0);
    pack_a<FP32IN>(u1, f1, a1);

    // prefetch iteration-2 pair into the SAME arrays (now dead) — overlaps
    // the whole iteration-1 compute; compiler waits (vmcnt) only at pack #2.
    load_a_raw<AXIS, FP32IN>(Xv, rbase + 128 + wv * 16 + mr, u0, f0, kq);
    load_a_raw<AXIS, FP32IN>(Xv, rbase + 192 + wv * 16 + mr, u1, f1, kq);

    f32x4 acc0[10] = {};
    f32x4 acc1[10] = {};
    tile_compute_both(lw, a0, a1, acc0, acc1, mr, kq);
    if (F32OUT) {
        store_f32_direct(acc0, Bs, (float*)Yv, rbase + wv * 16, mr, kq);
        store_f32_direct(acc1, Bs, (float*)Yv, rbase + 64 + wv * 16, mr, kq);
    } else {
        store_bf16_staged(stg, acc0, Bs, (unsigned short*)Yv, rbase + wv * 16, lane, wv, mr, kq);
        store_bf16_staged(stg, acc1, Bs, (unsigned short*)Yv, rbase + 64 + wv * 16, lane, wv, mr, kq);
    }

    // iteration 2 (W still in lw; staging slots reused per-wave, in-order DS)
    pack_a<FP32IN>(u0, f0, a0);
    pack_a<FP32IN>(u1, f1, a1);
#pragma unroll
    for (int nt = 0; nt < 10; nt++) { acc0[nt] = f32x4{0, 0, 0, 0}; acc1[nt] = f32x4{0, 0, 0, 0}; }
    tile_compute_both(lw, a0, a1, acc0, acc1, mr, kq);
    if (F32OUT) {
        store_f32_direct(acc0, Bs, (float*)Yv, rbase + 128 + wv * 16, mr, kq);
        store_f32_direct(acc1, Bs, (float*)Yv, rbase + 192 + wv * 16, mr, kq);
    } else {
        store_bf16_staged(stg, acc0, Bs, (unsigned short*)Yv, rbase + 128 + wv * 16, lane, wv, mr, kq);
        store_bf16_staged(stg, acc1, Bs, (unsigned short*)Yv, rbase + 192 + wv * 16, lane, wv, mr, kq);
    }
}

// ---------------------------------------------------------------------------
// Depthwise 3x3x3 SAME conv + bias. (R8 XCD chunk swizzle kept; UNCHANGED.)
// ---------------------------------------------------------------------------
__global__ __launch_bounds__(256) void dwconv3(
    const unsigned short* __restrict__ X, const float* __restrict__ Kw,
    const float* __restrict__ Bs, unsigned short* __restrict__ Y) {
    __shared__ float wl[20 * 220];
    const int t = threadIdx.x;
    for (int e = t; e < 160 * 27; e += 256) {
        int c = e / 27, tap = e % 27;
        wl[(c >> 3) * 220 + tap * 8 + (c & 7)] = Kw[e];
    }
    __syncthreads();

    // bijective XCD swizzle: 2560 blocks = 8 XCDs x 320-block contiguous chunks
    int bid = blockIdx.x;
    int swz = (bid & 7) * 320 + (bid >> 3);
    int idx = swz * 256 + t;

    int cc = idx % 20;
    int r = idx / 20;
    int dq = r & 7;  r >>= 3;
    int w = r & 31;  r >>= 5;
    int h = r & 31;
    int b = r >> 5;
    int d0 = dq << 2;

    float acc[4][8];
    {
        float bv[8];
        *(float4*)&bv[0] = ((const float4*)(Bs + cc * 8))[0];
        *(float4*)&bv[4] = ((const float4*)(Bs + cc * 8))[1];
#pragma unroll
        for (int od = 0; od < 4; od++)
#pragma unroll
            for (int j = 0; j < 8; j++) acc[od][j] = bv[j];
    }
    const float* wbase = &wl[cc * 220];
#pragma unroll
    for (int dh = -1; dh <= 1; dh++) {
        int hh = h + dh;
        if ((unsigned)hh >= 32u) continue;
#pragma unroll
        for (int dwi = -1; dwi <= 1; dwi++) {
            int ww = w + dwi;
            if ((unsigned)ww >= 32u) continue;
            const unsigned short* base =
                X + (size_t)(b * 32768 + hh * 1024 + ww * 32) * 160 + cc * 8;
            int tap0 = (dh + 1) * 9 + (dwi + 1) * 3;
            float wv_[24];
#pragma unroll
            for (int q2 = 0; q2 < 6; q2++)
                ((float4*)wv_)[q2] = *(const float4*)(wbase + tap0 * 8 + q2 * 4);
            // hoist the 6 raw loads, then convert (independent issue)
            uint4 ub[6];
#pragma unroll
            for (int dd = 0; dd < 6; dd++) {
                int d = d0 - 1 + dd;
                ub[dd] = ((unsigned)d < 32u) ? *(const uint4*)(base + d * 160)
                                             : make_uint4(0, 0, 0, 0);
            }
            float vb[6][8];
#pragma unroll
            for (int dd = 0; dd < 6; dd++) cvt8(ub[dd], vb[dd]);
#pragma unroll
            for (int od = 0; od < 4; od++)
#pragma unroll
                for (int dd = 0; dd < 3; dd++)
#pragma unroll
                    for (int j = 0; j < 8; j++)
                        acc[od][j] += vb[od + dd][j] * wv_[dd * 8 + j];
        }
    }
#pragma unroll
    for (int od = 0; od < 4; od++) {
        unsigned short tmp[8];
#pragma unroll
        for (int j = 0; j < 8; j++) tmp[j] = f2bf(acc[od][j]);
        *(uint4*)(Y + (size_t)(b * 32768 + h * 1024 + w * 32 + d0 + od) * 160 + cc * 8) =
            *(uint4*)tmp;
    }
}

// ---------------------------------------------------------------------------
// Pipeline: prep_w3 -> shiftH+GEMM1 -> dw1 -> shiftW+GEMM2 -> dw2 ->
//           shiftD+GEMM3+GELU.  Intermediates in d_ws (R9 layout kept).
// ---------------------------------------------------------------------------
extern "C" void kernel_launch(void* const* d_in, const int* in_sizes, int n_in,
                              void* d_out, int out_size, void* d_ws, size_t ws_size,
                              hipStream_t stream) {
    const void*  x    = d_in[0];                    // fp32 (B,N,C)
    const float* w1   = (const float*)d_in[4];
    const float* b1   = (const float*)d_in[5];
    const float* dw1  = (const float*)d_in[6];
    const float* bdw1 = (const float*)d_in[7];
    const float* w2   = (const float*)d_in[8];
    const float* b2   = (const float*)d_in[9];
    const float* dw2  = (const float*)d_in[10];
    const float* bdw2 = (const float*)d_in[11];
    const float* w3   = (const float*)d_in[12];
    const float* b3   = (const float*)d_in[13];

    unsigned short* wbf = (unsigned short*)d_ws;   // 3 x WELEMS bf16 W^T padded

    const size_t BUF_BYTES = (size_t)4 * 32768 * 160 * 2;  // 41,943,040 B
    const size_t OFF_A = 2u << 20;                          // 2 MiB
    const size_t OFF_B = OFF_A + BUF_BYTES;
    unsigned short* bufA;
    unsigned short* bufB;
    if (ws_size >= OFF_B + BUF_BYTES) {
        bufA = (unsigned short*)((char*)d_ws + OFF_A);      // clean: ws only
        bufB = (unsigned short*)((char*)d_ws + OFF_B);
    } else {
        bufA = (unsigned short*)d_out;                      // fallback
        bufB = (unsigned short*)d_in[0];
    }

    prep_w3<<<315, 256, 0, stream>>>(w1, w2, w3, wbf);
    gemm_shift<0, false, true,  false><<<512, 256, 0, stream>>>(x,    wbf,              b1, bufA);
    dwconv3<<<2560, 256, 0, stream>>>(bufA, dw1, bdw1, bufB);
    gemm_shift<1, false, false, false><<<512, 256, 0, stream>>>(bufB, wbf + WELEMS,     b2, bufA);
    dwconv3<<<2560, 256, 0, stream>>>(bufA, dw2, bdw2, bufB);
    gemm_shift<2, true,  false, true ><<<512, 256, 0, stream>>>(bufB, wbf + 2 * WELEMS, b3, d_out);
}

// Round 9
// 297.998 us; speedup vs baseline: 1.1752x; 1.0186x over previous
//
#include <hip/hip_runtime.h>

typedef __bf16 bf16x8 __attribute__((ext_vector_type(8)));
typedef float f32x4 __attribute__((ext_vector_type(4)));

__device__ inline unsigned short f2bf(float f) {
    unsigned x = __builtin_bit_cast(unsigned, f);
    x += 0x7fffu + ((x >> 16) & 1u);   // RNE
    return (unsigned short)(x >> 16);
}
__device__ inline unsigned pack2bf(float lo, float hi) {
    return (unsigned)f2bf(lo) | ((unsigned)f2bf(hi) << 16);
}
__device__ inline void cvt8(uint4 u, float* o) {
    o[0] = __builtin_bit_cast(float, u.x << 16);
    o[1] = __builtin_bit_cast(float, u.x & 0xffff0000u);
    o[2] = __builtin_bit_cast(float, u.y << 16);
    o[3] = __builtin_bit_cast(float, u.y & 0xffff0000u);
    o[4] = __builtin_bit_cast(float, u.z << 16);
    o[5] = __builtin_bit_cast(float, u.z & 0xffff0000u);
    o[6] = __builtin_bit_cast(float, u.w << 16);
    o[7] = __builtin_bit_cast(float, u.w & 0xffff0000u);
}
// exact-erf GELU via Abramowitz-Stegun 7.1.26 (|err| <= 1.5e-7)
__device__ inline float gelu_f(float v) {
    float x = fabsf(v) * 0.70710678118654752f;
    float td = __builtin_amdgcn_rcpf(1.0f + 0.3275911f * x);
    float p = ((((1.061405429f * td - 1.453152027f) * td + 1.421413741f) * td
                - 0.284496736f) * td + 0.254829592f) * td;
    float e = __expf(-x * x);
    float er = 1.0f - p * e;
    float s = v < 0.0f ? -er : er;
    return 0.5f * v * (1.0f + s);
}

// async global->LDS, 16B per lane (emits global_load_lds_dwordx4)
__device__ inline void gload_lds16(const void* g, void* l) {
    typedef __attribute__((address_space(1))) const unsigned int gq;
    typedef __attribute__((address_space(3))) unsigned int sq;
    __builtin_amdgcn_global_load_lds((gq*)g, (sq*)l, 16, 0, 0);
}

#define WPAD 168
#define WELEMS (160 * WPAD)             // full matrix: 26880 shorts
#define WHALF_ROWS 80
#define WHALF_ELEMS (WHALF_ROWS * WPAD) // 13440 shorts
#define WHALF_CHUNKS (WHALF_ELEMS * 2 / 16)  // 1680 16B chunks
#define SPAD 88                          // staged-row pad: 176B, 16B-aligned rows

// ---------------------------------------------------------------------------
// prep_w3: all three W (fp32 160x160) -> bf16 W^T, PADDED [co][WPAD], in d_ws.
// ---------------------------------------------------------------------------
__global__ __launch_bounds__(256) void prep_w3(const float* __restrict__ W1,
                                               const float* __restrict__ W2,
                                               const float* __restrict__ W3,
                                               unsigned short* __restrict__ dst) {
    int e = blockIdx.x * 256 + threadIdx.x;  // 3*WELEMS = 80640 total
    if (e >= 3 * WELEMS) return;
    int m = e / WELEMS;
    int r = e - m * WELEMS;
    int co = r / WPAD, ci = r - co * WPAD;
    const float* W = (m == 0) ? W1 : (m == 1) ? W2 : W3;
    dst[e] = (ci < 160) ? f2bf(W[ci * 160 + co]) : (unsigned short)0;
}

template <int AXIS, bool FP32IN>
__device__ inline void load_a_raw(const void* __restrict__ Xv, int row, uint4* u,
                                  float4* f, int kq) {
    const int n = row & 32767;
    const int coord = (AXIS == 0) ? (n >> 10) : (AXIS == 1) ? ((n >> 5) & 31) : (n & 31);
    const int stride = (AXIS == 0) ? 1024 : (AXIS == 1) ? 32 : 1;
#pragma unroll
    for (int g = 0; g < 5; g++) {
        int s = 2 - g;
        bool ok = (unsigned)(coord + s) < 32u;
        int srow = ok ? row + s * stride : row;
        size_t off = (size_t)srow * 160 + g * 32 + kq * 8;
        if (FP32IN) {
            const float* p = (const float*)Xv + off;
            float4 r0 = ((const float4*)p)[0];
            float4 r1 = ((const float4*)p)[1];
            if (!ok) { r0 = make_float4(0, 0, 0, 0); r1 = make_float4(0, 0, 0, 0); }
            f[g * 2] = r0; f[g * 2 + 1] = r1;
        } else {
            uint4 v = *(const uint4*)((const unsigned short*)Xv + off);
            if (!ok) v = make_uint4(0, 0, 0, 0);
            u[g] = v;
        }
    }
}

template <bool FP32IN>
__device__ inline void pack_a(const uint4* u, const float4* f, uint4* a) {
#pragma unroll
    for (int g = 0; g < 5; g++) {
        if (FP32IN) {
            float4 r0 = f[g * 2], r1 = f[g * 2 + 1];
            a[g] = make_uint4(pack2bf(r0.x, r0.y), pack2bf(r0.z, r0.w),
                              pack2bf(r1.x, r1.y), pack2bf(r1.z, r1.w));
        } else {
            a[g] = u[g];
        }
    }
}

// Half-N compute: 5 nt tiles (80 cols). acc[nt][r] = Y[xrow][co0 + nt*16+kq*4+r].
__device__ inline void tile_compute_both_h(const unsigned short* __restrict__ lw,
                                           const uint4* a0, const uint4* a1,
                                           f32x4* acc0, f32x4* acc1, int mr, int kq) {
#pragma unroll
    for (int g = 0; g < 5; g++) {
        bf16x8 x0 = __builtin_bit_cast(bf16x8, a0[g]);
        bf16x8 x1 = __builtin_bit_cast(bf16x8, a1[g]);
        const unsigned short* bp = lw + mr * WPAD + g * 32 + kq * 8;
#pragma unroll
        for (int nt = 0; nt < 5; nt++) {
            bf16x8 wf = __builtin_bit_cast(bf16x8, *(const uint4*)(bp + nt * 16 * WPAD));
            acc0[nt] = __builtin_amdgcn_mfma_f32_16x16x32_bf16(wf, x0, acc0[nt], 0, 0, 0);
            acc1[nt] = __builtin_amdgcn_mfma_f32_16x16x32_bf16(wf, x1, acc1[nt], 0, 0, 0);
        }
    }
}

// bf16 epilogue: stage wave's 16x80 half-strip in LDS (row pad SPAD=88 keeps
// 16B-aligned rows), then coalesced uint4 stores of 160B strips.
__device__ inline void store_bf16_staged_h(unsigned short* __restrict__ stg,
                                           const f32x4* acc, const float* __restrict__ Bs,
                                           unsigned short* __restrict__ Yv, int rowbase,
                                           int co0, int lane, int wv, int mr, int kq) {
    unsigned short* sw = stg + wv * (16 * SPAD);
#pragma unroll
    for (int nt = 0; nt < 5; nt++) {
        float4 bb = *(const float4*)(Bs + co0 + nt * 16 + kq * 4);
        uint2 pk;
        pk.x = pack2bf(acc[nt][0] + bb.x, acc[nt][1] + bb.y);
        pk.y = pack2bf(acc[nt][2] + bb.z, acc[nt][3] + bb.w);
        *(uint2*)(sw + mr * SPAD + nt * 16 + kq * 4) = pk;
    }
    // 16 rows x 80 shorts = 1280 shorts; 8 shorts (16B) per lane per pass
#pragma unroll
    for (int p = 0; p < 3; p++) {
        int idx = p * 512 + lane * 8;
        if (p == 2 && lane >= 32) break;
        int row = idx / 80;
        int col = idx - row * 80;
        uint4 v = *(const uint4*)(sw + row * SPAD + col);
        *(uint4*)(Yv + (size_t)(rowbase + row) * 160 + co0 + col) = v;
    }
}

// fp32 epilogue (+GELU): direct stores — 80-float strip = 320B, 64B-aligned
// (co0*4 = 0 or 320): full HBM sectors, no staging, no barrier.
__device__ inline void store_f32_direct_h(const f32x4* acc, const float* __restrict__ Bs,
                                          float* __restrict__ Yv, int rowbase,
                                          int co0, int mr, int kq) {
    float* rp = Yv + (size_t)(rowbase + mr) * 160 + co0;
#pragma unroll
    for (int nt = 0; nt < 5; nt++) {
        float4 bb = *(const float4*)(Bs + co0 + nt * 16 + kq * 4);
        float4 v;
        v.x = gelu_f(acc[nt][0] + bb.x);
        v.y = gelu_f(acc[nt][1] + bb.y);
        v.z = gelu_f(acc[nt][2] + bb.z);
        v.w = gelu_f(acc[nt][3] + bb.w);
        *(float4*)(rp + nt * 16 + kq * 4) = v;
    }
}

// ---------------------------------------------------------------------------
// R13: N-split for occupancy. Each block: 128 rows x 80 output channels.
// LDS: 26.9KB W-half (+11.3KB staging for bf16) -> 3-4 blocks/CU (was 2 at
// 53.8KB). R9 vs R12 showed W-traffic/barriers don't matter — latency hiding
// (resident waves) does. Chunked XCD swizzle puts the two co-halves of a
// row-panel 8 bids apart -> same XCD, temporally adjacent -> shared A-panel
// is one HBM fetch + one L2 hit (A FETCH stays flat).
// ---------------------------------------------------------------------------
template <int AXIS, bool GELU, bool FP32IN, bool F32OUT>
__global__ __launch_bounds__(256, 4) void gemm_shift(
    const void* __restrict__ Xv, const unsigned short* __restrict__ Wt,
    const float* __restrict__ Bs, void* __restrict__ Yv) {
    __shared__ unsigned short lw[WHALF_ELEMS];                 // 26880 B
    __shared__ unsigned short stg[F32OUT ? 1 : 4 * 16 * SPAD]; // 11264 B (bf16 only)
    const int t = threadIdx.x;
    const int lane = t & 63, wv = t >> 6, mr = lane & 15, kq = lane >> 4;

    // bijective chunked swizzle: 2048 blocks -> swz; pair (2k,2k+1) = bids 8
    // apart = same XCD under round-robin, contiguous per-XCD ranges.
    int bid = blockIdx.x;
    int swz = (bid & 7) * 256 + (bid >> 3);
    const int rowblk = swz >> 1;
    const int cohalf = swz & 1;
    const int rbase = rowblk * 128;
    const int co0 = cohalf * 80;
    const unsigned short* wth = Wt + cohalf * WHALF_ELEMS;

    // async W-half DMA first (no VGPR use): 1680 16B chunks
    for (int i = t; i < WHALF_CHUNKS; i += 256)
        gload_lds16((const char*)wth + i * 16, (char*)lw + i * 16);

    // prefetch BOTH A tiles (full K) while the DMA flows
    uint4 u0[5], u1[5];
    float4 f0[10], f1[10];
    load_a_raw<AXIS, FP32IN>(Xv, rbase + wv * 16 + mr, u0, f0, kq);
    load_a_raw<AXIS, FP32IN>(Xv, rbase + 64 + wv * 16 + mr, u1, f1, kq);

    __syncthreads();  // drains vmcnt: W DMA + A loads. ONLY barrier.

    uint4 a0[5], a1[5];
    pack_a<FP32IN>(u0, f0, a0);
    pack_a<FP32IN>(u1, f1, a1);
    f32x4 acc0[5] = {};
    f32x4 acc1[5] = {};
    tile_compute_both_h(lw, a0, a1, acc0, acc1, mr, kq);

    if (F32OUT) {
        store_f32_direct_h(acc0, Bs, (float*)Yv, rbase + wv * 16, co0, mr, kq);
        store_f32_direct_h(acc1, Bs, (float*)Yv, rbase + 64 + wv * 16, co0, mr, kq);
    } else {
        store_bf16_staged_h(stg, acc0, Bs, (unsigned short*)Yv, rbase + wv * 16,
                            co0, lane, wv, mr, kq);
        store_bf16_staged_h(stg, acc1, Bs, (unsigned short*)Yv, rbase + 64 + wv * 16,
                            co0, lane, wv, mr, kq);
    }
}

// ---------------------------------------------------------------------------
// Depthwise 3x3x3 SAME conv + bias. (R8 XCD chunk swizzle kept; UNCHANGED.)
// ---------------------------------------------------------------------------
__global__ __launch_bounds__(256) void dwconv3(
    const unsigned short* __restrict__ X, const float* __restrict__ Kw,
    const float* __restrict__ Bs, unsigned short* __restrict__ Y) {
    __shared__ float wl[20 * 220];
    const int t = threadIdx.x;
    for (int e = t; e < 160 * 27; e += 256) {
        int c = e / 27, tap = e % 27;
        wl[(c >> 3) * 220 + tap * 8 + (c & 7)] = Kw[e];
    }
    __syncthreads();

    // bijective XCD swizzle: 2560 blocks = 8 XCDs x 320-block contiguous chunks
    int bid = blockIdx.x;
    int swz = (bid & 7) * 320 + (bid >> 3);
    int idx = swz * 256 + t;

    int cc = idx % 20;
    int r = idx / 20;
    int dq = r & 7;  r >>= 3;
    int w = r & 31;  r >>= 5;
    int h = r & 31;
    int b = r >> 5;
    int d0 = dq << 2;

    float acc[4][8];
    {
        float bv[8];
        *(float4*)&bv[0] = ((const float4*)(Bs + cc * 8))[0];
        *(float4*)&bv[4] = ((const float4*)(Bs + cc * 8))[1];
#pragma unroll
        for (int od = 0; od < 4; od++)
#pragma unroll
            for (int j = 0; j < 8; j++) acc[od][j] = bv[j];
    }
    const float* wbase = &wl[cc * 220];
#pragma unroll
    for (int dh = -1; dh <= 1; dh++) {
        int hh = h + dh;
        if ((unsigned)hh >= 32u) continue;
#pragma unroll
        for (int dwi = -1; dwi <= 1; dwi++) {
            int ww = w + dwi;
            if ((unsigned)ww >= 32u) continue;
            const unsigned short* base =
                X + (size_t)(b * 32768 + hh * 1024 + ww * 32) * 160 + cc * 8;
            int tap0 = (dh + 1) * 9 + (dwi + 1) * 3;
            float wv_[24];
#pragma unroll
            for (int q2 = 0; q2 < 6; q2++)
                ((float4*)wv_)[q2] = *(const float4*)(wbase + tap0 * 8 + q2 * 4);
            // hoist the 6 raw loads, then convert (independent issue)
            uint4 ub[6];
#pragma unroll
            for (int dd = 0; dd < 6; dd++) {
                int d = d0 - 1 + dd;
                ub[dd] = ((unsigned)d < 32u) ? *(const uint4*)(base + d * 160)
                                             : make_uint4(0, 0, 0, 0);
            }
            float vb[6][8];
#pragma unroll
            for (int dd = 0; dd < 6; dd++) cvt8(ub[dd], vb[dd]);
#pragma unroll
            for (int od = 0; od < 4; od++)
#pragma unroll
                for (int dd = 0; dd < 3; dd++)
#pragma unroll
                    for (int j = 0; j < 8; j++)
                        acc[od][j] += vb[od + dd][j] * wv_[dd * 8 + j];
        }
    }
#pragma unroll
    for (int od = 0; od < 4; od++) {
        unsigned short tmp[8];
#pragma unroll
        for (int j = 0; j < 8; j++) tmp[j] = f2bf(acc[od][j]);
        *(uint4*)(Y + (size_t)(b * 32768 + h * 1024 + w * 32 + d0 + od) * 160 + cc * 8) =
            *(uint4*)tmp;
    }
}

// ---------------------------------------------------------------------------
// Pipeline: prep_w3 -> shiftH+GEMM1 -> dw1 -> shiftW+GEMM2 -> dw2 ->
//           shiftD+GEMM3+GELU.  Intermediates in d_ws (R9 layout kept).
// ---------------------------------------------------------------------------
extern "C" void kernel_launch(void* const* d_in, const int* in_sizes, int n_in,
                              void* d_out, int out_size, void* d_ws, size_t ws_size,
                              hipStream_t stream) {
    const void*  x    = d_in[0];                    // fp32 (B,N,C)
    const float* w1   = (const float*)d_in[4];
    const float* b1   = (const float*)d_in[5];
    const float* dw1  = (const float*)d_in[6];
    const float* bdw1 = (const float*)d_in[7];
    const float* w2   = (const float*)d_in[8];
    const float* b2   = (const float*)d_in[9];
    const float* dw2  = (const float*)d_in[10];
    const float* bdw2 = (const float*)d_in[11];
    const float* w3   = (const float*)d_in[12];
    const float* b3   = (const float*)d_in[13];

    unsigned short* wbf = (unsigned short*)d_ws;   // 3 x WELEMS bf16 W^T padded

    const size_t BUF_BYTES = (size_t)4 * 32768 * 160 * 2;  // 41,943,040 B
    const size_t OFF_A = 2u << 20;                          // 2 MiB
    const size_t OFF_B = OFF_A + BUF_BYTES;
    unsigned short* bufA;
    unsigned short* bufB;
    if (ws_size >= OFF_B + BUF_BYTES) {
        bufA = (unsigned short*)((char*)d_ws + OFF_A);      // clean: ws only
        bufB = (unsigned short*)((char*)d_ws + OFF_B);
    } else {
        bufA = (unsigned short*)d_out;                      // fallback
        bufB = (unsigned short*)d_in[0];
    }

    prep_w3<<<315, 256, 0, stream>>>(w1, w2, w3, wbf);
    gemm_shift<0, false, true,  false><<<2048, 256, 0, stream>>>(x,    wbf,              b1, bufA);
    dwconv3<<<2560, 256, 0, stream>>>(bufA, dw1, bdw1, bufB);
    gemm_shift<1, false, false, false><<<2048, 256, 0, stream>>>(bufB, wbf + WELEMS,     b2, bufA);
    dwconv3<<<2560, 256, 0, stream>>>(bufA, dw2, bdw2, bufB);
    gemm_shift<2, true,  false, true ><<<2048, 256, 0, stream>>>(bufB, wbf + 2 * WELEMS, b3, d_out);
}